// Round 4
// baseline (1033.157 us; speedup 1.0000x reference)
//
#include <hip/hip_runtime.h>
#include <math.h>

// Problem constants (fixed by setup_inputs)
#define NCH 128
#define IMW 640
#define IMH 480
#define HW (IMW * IMH)
#define THREADS 512
#define WPB (THREADS / 64)   // waves per block
#define GBLK 512             // fused partial blocks
#define TSTRIDE (3 * NCH)    // interleaved (pix, map, ch) stride = 384 floats

// state layout in d_ws (doubles)
#define S_R    0   // 9: current (accepted) R, row-major
#define S_T    9   // 3: current t
#define S_RC   12  // 9: candidate R
#define S_TC   21  // 3: candidate t
#define S_LAM  24
#define S_LR   25
#define S_PREV 26
#define S_G    32  // 27: stashed reduced Grad(6) + Hess upper-tri(21) at accepted pose
#define S_TOTAL 64

#define PCOLS 29   // per-block partials: 27 grad/hess + cost-sum + count

struct ProjR {
  float x, y, z;
  int pix;
  bool m;
};

__device__ __forceinline__ ProjR project_pt(const float* __restrict__ pts, int n,
                                            const float R[9], const float T[3],
                                            const float Kv[9]) {
  float px = pts[3 * n + 0], py = pts[3 * n + 1], pz = pts[3 * n + 2];
  ProjR o;
  o.x = R[0] * px + R[1] * py + R[2] * pz + T[0];
  o.y = R[3] * px + R[4] * py + R[5] * pz + T[1];
  o.z = R[6] * px + R[7] * py + R[8] * pz + T[2];
  float pr0 = Kv[0] * o.x + Kv[1] * o.y + Kv[2] * o.z;
  float pr1 = Kv[3] * o.x + Kv[4] * o.y + Kv[5] * o.z;
  float pr2 = Kv[6] * o.x + Kv[7] * o.y + Kv[8] * o.z;
  float u = fminf(fmaxf(pr0 / pr2, -1000000.0f), 1000000.0f);
  float v = fminf(fmaxf(pr1 / pr2, -1000000.0f), 1000000.0f);
  int p2x = (int)rintf(u) - 1;   // round-half-even matches jnp.round
  int p2y = (int)rintf(v) - 1;
  o.m = (p2x >= 0) && (p2y >= 0) && (p2x < IMW) && (p2y < IMH);
  int r = min(max(p2y, 0), IMH - 1);
  int c = min(max(p2x, 0), IMW - 1);
  o.pix = r * IMW + c;
  return o;
}

// Per-point 2x6 Jacobian rows A0, A1
__device__ __forceinline__ void jac_rows(const ProjR& p, float fx, float fy,
                                         float A0[6], float A1[6]) {
  float Zs = (fabsf(p.z) > 1e-6f) ? p.z : 1e-6f;
  float iz = 1.0f / Zs;
  float j00 = fx * iz;
  float j02 = -fx * p.x * iz * iz;
  float j11 = fy * iz;
  float j12 = -fy * p.y * iz * iz;
  A0[0] = j00; A0[1] = 0.0f; A0[2] = j02;
  A0[3] = j02 * p.y; A0[4] = j00 * p.z - j02 * p.x; A0[5] = -j00 * p.y;
  A1[0] = 0.0f; A1[1] = j11; A1[2] = j12;
  A1[3] = -j11 * p.z + j12 * p.y; A1[4] = -j12 * p.x; A1[5] = j11 * p.x;
}

__global__ void init_kernel(const float* __restrict__ Rin,
                            const float* __restrict__ tin,
                            double* __restrict__ st) {
  int i = threadIdx.x;
  if (i < 9) { st[S_R + i] = (double)Rin[i]; st[S_RC + i] = (double)Rin[i]; }
  if (i < 3) { st[S_T + i] = (double)tin[i]; st[S_TC + i] = (double)tin[i]; }
  if (i == 0) { st[S_LAM] = 0.01; st[S_LR] = 1.0; st[S_PREV] = 0.0; }
}

// ---- (C,H,W) -> interleaved (pix, map, ch) transpose, all 3 maps ----
// LDS as float4 tile4[pix][ch4] with XOR swizzle col4 ^= (row>>2):
//  - write phase (4 scalar stores per loaded float4): banks spread 2-way (free)
//  - read phase (b128 per lane): permutation of 16B cells in a 512B row,
//    conflict-free.  (was: 1.47e7 conflict cycles/dispatch with padded tile)
__global__ __launch_bounds__(256) void transpose3_kernel(
    const float* __restrict__ f, const float* __restrict__ gx,
    const float* __restrict__ gy, float* __restrict__ t) {
  __shared__ float4 tile4[64][32];
  const int map = blockIdx.y;
  const float* in = (map == 0) ? f : (map == 1) ? gx : gy;
  const int pix0 = blockIdx.x * 64;
#pragma unroll
  for (int mm = 0; mm < 8; ++mm) {
    int k = threadIdx.x + 256 * mm;   // 0..2047
    int c  = k >> 4;                  // channel 0..127
    int p4 = (k & 15) * 4;            // pixel base (row), multiple of 4
    float4 v = ((const float4*)(in + (size_t)c * HW + pix0))[k & 15];
    int sw = (c >> 2) ^ (k & 15);     // (row>>2) == k&15 for all 4 rows
    int e  = c & 3;
    ((float*)&tile4[p4 + 0][sw])[e] = v.x;
    ((float*)&tile4[p4 + 1][sw])[e] = v.y;
    ((float*)&tile4[p4 + 2][sw])[e] = v.z;
    ((float*)&tile4[p4 + 3][sw])[e] = v.w;
  }
  __syncthreads();
#pragma unroll
  for (int mm = 0; mm < 8; ++mm) {
    int k = threadIdx.x + 256 * mm;
    int px = k >> 5;                  // pixel 0..63
    int c4 = k & 31;                  // float4 channel group
    float4 v = tile4[px][c4 ^ (px >> 2)];
    ((float4*)(t + (size_t)(pix0 + px) * TSTRIDE + (size_t)map * NCH))[c4] = v;
  }
}

// ---- fused cost+grad at CANDIDATE pose ----
// LM identity: grad/Hess at a pose is pose-pure; accept adopts the stash,
// reject reuses it -> one fused pass per iteration.
// Restructure vs previous version:
//  * 2 points per wave (lanes 0-31 = point A, 32-63 = point B), float4
//    (4-channel) gathers per lane.
//  * swap sum order: per-LANE f32 accumulation of all 27 grad/Hess
//    quantities (27 independent FMA chains, pure ILP) -- the 6-step
//    cross-lane shuffle reduce runs ONCE per kernel, not once per point.
//    (old: 30 DS-pipe ops serial per point = latency wall)
//  * masking via multiply (matches reference clamped-gather * m semantics).
// Partials: [0..26] grad(6)+hess(21), [27] sum(err^2), [28] count.
template <bool TRANS>
__global__ __launch_bounds__(THREADS) void fused_kernel(
    const float* __restrict__ pts, const float* __restrict__ fref,
    const float* __restrict__ mf, const float* __restrict__ mgx,
    const float* __restrict__ mgy, const float* __restrict__ Kmat,
    const double* __restrict__ st, double* __restrict__ part, int N) {
  const int lane = threadIdx.x & 63;
  const int wib  = threadIdx.x >> 6;
  const int gw = blockIdx.x * WPB + wib;
  const int nw = gridDim.x * WPB;
  const int half = lane >> 5;     // which point of the pair
  const int hl   = lane & 31;     // lane within half: channels 4*hl..4*hl+3

  float R[9], T[3], Kv[9];
#pragma unroll
  for (int i = 0; i < 9; ++i) { R[i] = (float)st[S_RC + i]; Kv[i] = Kmat[i]; }
#pragma unroll
  for (int i = 0; i < 3; ++i) T[i] = (float)st[S_TC + i];
  const float fx = Kv[0], fy = Kv[4];

  float hacc[27];
#pragma unroll
  for (int j = 0; j < 27; ++j) hacc[j] = 0.0f;
  double csum = 0.0;
  float cntf = 0.0f;

  for (int base = gw * 2; base < N; base += 2 * nw) {
    const int n = base + half;
    const int nc = min(n, N - 1);
    ProjR p = project_pt(pts, nc, R, T, Kv);
    const float m = (p.m && n < N) ? 1.0f : 0.0f;
    if (__all(m == 0.0f)) continue;

    float A0[6], A1[6];
    jac_rows(p, fx, fy, A0, A1);

    float e0, e1, e2, e3;
    float gxx, gxy, gyy, gxe, gye;
    if (TRANS) {
      const float4* t4 = (const float4*)mf;  // interleaved (pix, map, ch4)
      const size_t b = (size_t)p.pix * (TSTRIDE / 4) + hl;
      float4 fv = t4[b];
      float4 gv = t4[b + 32];
      float4 hv = t4[b + 64];
      float4 rv = ((const float4*)fref)[(size_t)nc * (NCH / 4) + hl];
      e0 = fv.x - rv.x; e1 = fv.y - rv.y; e2 = fv.z - rv.z; e3 = fv.w - rv.w;
      gxx = gv.x * gv.x + gv.y * gv.y + gv.z * gv.z + gv.w * gv.w;
      gxy = gv.x * hv.x + gv.y * hv.y + gv.z * hv.z + gv.w * hv.w;
      gyy = hv.x * hv.x + hv.y * hv.y + hv.z * hv.z + hv.w * hv.w;
      gxe = gv.x * e0 + gv.y * e1 + gv.z * e2 + gv.w * e3;
      gye = hv.x * e0 + hv.y * e1 + hv.z * e2 + hv.w * e3;
    } else {
      const int c0 = hl * 4;
      const size_t bb = (size_t)p.pix;
      float f0 = mf[(size_t)(c0 + 0) * HW + bb];
      float f1 = mf[(size_t)(c0 + 1) * HW + bb];
      float f2 = mf[(size_t)(c0 + 2) * HW + bb];
      float f3 = mf[(size_t)(c0 + 3) * HW + bb];
      float gx0 = mgx[(size_t)(c0 + 0) * HW + bb];
      float gx1 = mgx[(size_t)(c0 + 1) * HW + bb];
      float gx2 = mgx[(size_t)(c0 + 2) * HW + bb];
      float gx3 = mgx[(size_t)(c0 + 3) * HW + bb];
      float gy0 = mgy[(size_t)(c0 + 0) * HW + bb];
      float gy1 = mgy[(size_t)(c0 + 1) * HW + bb];
      float gy2 = mgy[(size_t)(c0 + 2) * HW + bb];
      float gy3 = mgy[(size_t)(c0 + 3) * HW + bb];
      float4 rv = ((const float4*)fref)[(size_t)nc * (NCH / 4) + hl];
      e0 = f0 - rv.x; e1 = f1 - rv.y; e2 = f2 - rv.z; e3 = f3 - rv.w;
      gxx = gx0 * gx0 + gx1 * gx1 + gx2 * gx2 + gx3 * gx3;
      gxy = gx0 * gy0 + gx1 * gy1 + gx2 * gy2 + gx3 * gy3;
      gyy = gy0 * gy0 + gy1 * gy1 + gy2 * gy2 + gy3 * gy3;
      gxe = gx0 * e0 + gx1 * e1 + gx2 * e2 + gx3 * e3;
      gye = gy0 * e0 + gy1 * e1 + gy2 * e2 + gy3 * e3;
    }

    gxx *= m; gxy *= m; gyy *= m; gxe *= m; gye *= m;
    csum += (double)(m * (e0 * e0 + e1 * e1 + e2 * e2 + e3 * e3));
    if (hl == 0) cntf += m;

    // grad
#pragma unroll
    for (int k = 0; k < 6; ++k) hacc[k] += gxe * A0[k] + gye * A1[k];
    // hess: H_kl += u_k*A0[l] + v_k*A1[l], u_k = gxx*A0k + gxy*A1k,
    //                                       v_k = gxy*A0k + gyy*A1k
    float u[6], v[6];
#pragma unroll
    for (int k = 0; k < 6; ++k) {
      u[k] = gxx * A0[k] + gxy * A1[k];
      v[k] = gxy * A0[k] + gyy * A1[k];
    }
    int q = 6;
#pragma unroll
    for (int k = 0; k < 6; ++k)
#pragma unroll
      for (int l = k; l < 6; ++l) {
        hacc[q] += u[k] * A0[l] + v[k] * A1[l];
        ++q;
      }
  }

  // one-time wave reduce (double) + block reduce
  __shared__ double red[WPB][PCOLS];
#pragma unroll
  for (int j = 0; j < 27; ++j) {
    double d = (double)hacc[j];
#pragma unroll
    for (int off = 32; off > 0; off >>= 1) d += __shfl_xor(d, off);
    if (lane == 0) red[wib][j] = d;
  }
  {
    double cs = csum;
    float cf = cntf;
#pragma unroll
    for (int off = 32; off > 0; off >>= 1) {
      cs += __shfl_xor(cs, off);
      cf += __shfl_xor(cf, off);
    }
    if (lane == 0) { red[wib][27] = cs; red[wib][28] = (double)cf; }
  }
  __syncthreads();
  if (wib == 0 && lane < PCOLS) {
    double s = 0.0;
#pragma unroll
    for (int w = 0; w < WPB; ++w) s += red[w][lane];
    part[(size_t)blockIdx.x * PCOLS + lane] = s;
  }
}

// Reduce partials; accept/reject; stash grads on accept; LM solve next
// candidate with UPDATED lambda/lr; write output pose.
__global__ void update_solve_kernel(const double* __restrict__ part, int GB,
                                    double* __restrict__ st,
                                    float* __restrict__ out, int is_init) {
  __shared__ double red[16][PCOLS];
  __shared__ double tot[PCOLS];
  int q = threadIdx.x & 31;
  int chunk = threadIdx.x >> 5;  // 0..15
  if (q < PCOLS) {
    double s = 0.0;
    for (int b = chunk; b < GB; b += 16) s += part[(size_t)b * PCOLS + q];
    red[chunk][q] = s;
  }
  __syncthreads();
  if (threadIdx.x < PCOLS) {
    double t = 0.0;
#pragma unroll
    for (int ch = 0; ch < 16; ++ch) t += red[ch][threadIdx.x];
    tot[threadIdx.x] = t;
  }
  __syncthreads();
  if (threadIdx.x == 0) {
    double nc = 0.5 * tot[27] / fmax(tot[28], 1.0);
    bool accept;
    if (is_init) {
      accept = true;
      st[S_PREV] = nc;
    } else {
      accept = (nc <= st[S_PREV]);
      double lam = st[S_LAM] * (accept ? 0.1 : 10.0);
      st[S_LAM] = fmin(fmax(lam, 1e-6), 1e4);
      st[S_LR] = accept ? 1.0 : fmin(fmax(0.1 * st[S_LR], 1e-3), 1.0);
      if (accept) st[S_PREV] = nc;
    }
    if (accept) {
      for (int i = 0; i < 9; ++i) st[S_R + i] = st[S_RC + i];
      for (int i = 0; i < 3; ++i) st[S_T + i] = st[S_TC + i];
      for (int j = 0; j < 27; ++j) st[S_G + j] = tot[j];
    }
    for (int i = 0; i < 9; ++i) out[i] = (float)st[S_R + i];
    for (int i = 0; i < 3; ++i) out[9 + i] = (float)st[S_T + i];

    // ---- LM solve for the NEXT candidate, using updated lam/lr ----
    double Grad[6], Hs[6][6];
    for (int j = 0; j < 6; ++j) Grad[j] = st[S_G + j];
    int qq = 0;
    for (int k = 0; k < 6; ++k)
      for (int l = k; l < 6; ++l) { Hs[k][l] = Hs[l][k] = st[S_G + 6 + qq]; ++qq; }
    double lam = st[S_LAM], lr = st[S_LR];
    double M[6][7];
    for (int i = 0; i < 6; ++i) {
      for (int j = 0; j < 6; ++j) M[i][j] = Hs[i][j];
      M[i][i] += lam * (Hs[i][i] + 1e-9);
      M[i][6] = Grad[i];
    }
    for (int c = 0; c < 6; ++c) {
      int piv = c;
      double mx = fabs(M[c][c]);
      for (int r = c + 1; r < 6; ++r) {
        double a = fabs(M[r][c]);
        if (a > mx) { mx = a; piv = r; }
      }
      if (piv != c)
        for (int j = 0; j < 7; ++j) {
          double tmp = M[c][j]; M[c][j] = M[piv][j]; M[piv][j] = tmp;
        }
      double pv = M[c][c];
      if (pv == 0.0) pv = 1e-30;
      for (int r = c + 1; r < 6; ++r) {
        double f = M[r][c] / pv;
        for (int j = c; j < 7; ++j) M[r][j] -= f * M[c][j];
      }
    }
    double xs[6];
    for (int i = 5; i >= 0; --i) {
      double v = M[i][6];
      for (int j = i + 1; j < 6; ++j) v -= M[i][j] * xs[j];
      double pv = M[i][i];
      if (pv == 0.0) pv = 1e-30;
      xs[i] = v / pv;
    }
    double dt[3] = {-lr * xs[0], -lr * xs[1], -lr * xs[2]};
    double dw[3] = {-lr * xs[3], -lr * xs[4], -lr * xs[5]};
    double th2 = dw[0] * dw[0] + dw[1] * dw[1] + dw[2] * dw[2];
    double th = sqrt(th2 + 1e-24);
    double a, b;
    if (th < 1e-4) { a = 1.0 - th2 / 6.0; b = 0.5 - th2 / 24.0; }
    else { a = sin(th) / th; b = (1.0 - cos(th)) / (th2 + 1e-24); }
    double W[3][3] = {{0, -dw[2], dw[1]}, {dw[2], 0, -dw[0]}, {-dw[1], dw[0], 0}};
    double W2[3][3];
    for (int i = 0; i < 3; ++i)
      for (int j = 0; j < 3; ++j) {
        double s = 0.0;
        for (int k = 0; k < 3; ++k) s += W[i][k] * W[k][j];
        W2[i][j] = s;
      }
    double dr[3][3];
    for (int i = 0; i < 3; ++i)
      for (int j = 0; j < 3; ++j)
        dr[i][j] = ((i == j) ? 1.0 : 0.0) + a * W[i][j] + b * W2[i][j];
    for (int i = 0; i < 3; ++i) {
      for (int j = 0; j < 3; ++j) {
        double s = 0.0;
        for (int k = 0; k < 3; ++k) s += dr[i][k] * st[S_R + k * 3 + j];
        st[S_RC + i * 3 + j] = s;
      }
      double s = 0.0;
      for (int k = 0; k < 3; ++k) s += dr[i][k] * st[S_T + k];
      st[S_TC + i] = s + dt[i];
    }
  }
}

extern "C" void kernel_launch(void* const* d_in, const int* in_sizes, int n_in,
                              void* d_out, int out_size, void* d_ws, size_t ws_size,
                              hipStream_t stream) {
  const float* pts  = (const float*)d_in[0];
  const float* fref = (const float*)d_in[1];
  const float* fm   = (const float*)d_in[2];
  const float* gxm  = (const float*)d_in[3];
  const float* gym  = (const float*)d_in[4];
  const float* Kmat = (const float*)d_in[5];
  const float* Rin  = (const float*)d_in[6];
  const float* tin  = (const float*)d_in[7];
  const int N = in_sizes[0] / 3;

  double* st = (double*)d_ws;
  double* part = st + S_TOTAL;
  float* out = (float*)d_out;

  const size_t state_doubles = S_TOTAL + (size_t)GBLK * PCOLS;
  const size_t map_floats = (size_t)HW * NCH;               // 39.32 M
  const size_t need_fast =
      state_doubles * sizeof(double) + 3 * map_floats * sizeof(float) + 256;

  init_kernel<<<1, 64, 0, stream>>>(Rin, tin, st);

  if (ws_size >= need_fast) {
    // fast path: transpose maps into one interleaved (pix, map, ch) buffer
    float* tmap = (float*)(st + state_doubles);
    transpose3_kernel<<<dim3(HW / 64, 3), 256, 0, stream>>>(fm, gxm, gym, tmap);
    // fused at init pose (S_RC == init): yields prev_cost AND grad at P1
    fused_kernel<true><<<GBLK, THREADS, 0, stream>>>(pts, fref, tmap, tmap, tmap,
                                                     Kmat, st, part, N);
    update_solve_kernel<<<1, 512, 0, stream>>>(part, GBLK, st, out, 1);
    for (int it = 0; it < 10; ++it) {
      fused_kernel<true><<<GBLK, THREADS, 0, stream>>>(pts, fref, tmap, tmap,
                                                       tmap, Kmat, st, part, N);
      update_solve_kernel<<<1, 512, 0, stream>>>(part, GBLK, st, out, 0);
    }
  } else {
    // fallback: gather directly from (C,H,W)
    fused_kernel<false><<<GBLK, THREADS, 0, stream>>>(pts, fref, fm, gxm, gym,
                                                      Kmat, st, part, N);
    update_solve_kernel<<<1, 512, 0, stream>>>(part, GBLK, st, out, 1);
    for (int it = 0; it < 10; ++it) {
      fused_kernel<false><<<GBLK, THREADS, 0, stream>>>(pts, fref, fm, gxm, gym,
                                                        Kmat, st, part, N);
      update_solve_kernel<<<1, 512, 0, stream>>>(part, GBLK, st, out, 0);
    }
  }
}